// Round 5
// baseline (38153.674 us; speedup 1.0000x reference)
//
#include <hip/hip_runtime.h>
#include <hip/hip_bf16.h>

// Problem constants
#define LAYERS 2
#define DIRS   2
#define FEAT   512
#define HDIM   256
#define BATCH  64
#define TLEN   1024
#define FIVEH  1280
#define CHUNK  64          // timesteps per chunk
#define NCHUNK (TLEN / CHUNK)
#define NW     8           // workgroups per direction in recurrence
#define RETRY_GUARD 2048   // bounded re-poll per unit: broken protocol -> reported failure, not hang

typedef short bf16x8 __attribute__((ext_vector_type(8)));
typedef float f32x4  __attribute__((ext_vector_type(4)));
typedef unsigned long long u64;

// Relaxed agent-scope atomics: compile to global_{load,store} ... sc0 sc1 —
// bypass L1/L2, coherent at the Infinity Cache across XCDs. Compiler-managed,
// so all store-data / load-use register hazards are tracked by LLVM's
// waitcnt pass (unlike inline-asm memory ops — the r3/r4 bug class).
#define ALOAD(p)    __hip_atomic_load((p),      __ATOMIC_RELAXED, __HIP_MEMORY_SCOPE_AGENT)
#define ASTORE(p,v) __hip_atomic_store((p),(v), __ATOMIC_RELAXED, __HIP_MEMORY_SCOPE_AGENT)

__device__ __forceinline__ unsigned short f2bf(float x) {
    unsigned u = __float_as_uint(x);
    unsigned r = (u + 0x7fffu + ((u >> 16) & 1u)) >> 16;
    return (unsigned short)r;
}
__device__ __forceinline__ float bf2f(unsigned short h) {
    return __uint_as_float(((unsigned)h) << 16);
}
__device__ __forceinline__ float sigf(float x) {
    return 1.0f / (1.0f + __expf(-x));
}
__device__ __forceinline__ float tanhfast(float x) {
    return 1.0f - 2.0f / (__expf(2.0f * x) + 1.0f);
}

// ---------------------------------------------------------------------------
// Transpose + cast: src fp32 [K][N] (per (l,d) slab) -> dst bf16 [N][K]
// ---------------------------------------------------------------------------
__global__ __launch_bounds__(256) void castT_kernel(
    const float* __restrict__ src, unsigned short* __restrict__ dst, int K, int N)
{
    __shared__ float tile[32][33];
    const int n0 = blockIdx.x * 32, k0 = blockIdx.y * 32;
    const size_t slab = (size_t)blockIdx.z * K * N;
    src += slab; dst += slab;
    const int tx = threadIdx.x & 31, ty = threadIdx.x >> 5;
    #pragma unroll
    for (int r = 0; r < 32; r += 8)
        tile[ty + r][tx] = src[(size_t)(k0 + ty + r) * N + (n0 + tx)];
    __syncthreads();
    #pragma unroll
    for (int r = 0; r < 32; r += 8)
        dst[(size_t)(n0 + ty + r) * K + (k0 + tx)] = f2bf(tile[tx][ty + r]);
}

// ---------------------------------------------------------------------------
// Projection GEMM for one chunk (unchanged, proven across r0-r3)
// ---------------------------------------------------------------------------
__global__ __launch_bounds__(256) void proj_kernel(
    const float* __restrict__ features,
    const unsigned short* __restrict__ x1,
    const unsigned short* __restrict__ Wx_t,   // [l][d][1280][512] bf16
    const unsigned short* __restrict__ Wp_t,   // [l][d][256][512]  bf16
    const float* __restrict__ bx, const float* __restrict__ bh,
    const float* __restrict__ bp,
    unsigned short* __restrict__ gx_c,
    unsigned short* __restrict__ px_c,
    int layer, int chunk)
{
    const int ntb = blockIdx.x;
    const int mt  = blockIdx.y;
    const int d   = blockIdx.z;
    const int tid = threadIdx.x;
    const int wave = tid >> 6, lane = tid & 63;

    __shared__ __align__(16) unsigned short Alds[64][40];
    __shared__ __align__(16) unsigned short Blds[64][40];

    const int n0 = ntb * 64;
    const bool isWx = (n0 < FIVEH);
    const unsigned short* Wt = isWx
        ? (Wx_t + ((size_t)(layer * 2 + d) * FIVEH + n0) * FEAT)
        : (Wp_t + ((size_t)(layer * 2 + d) * HDIM + (n0 - FIVEH)) * FEAT);

    const int m0 = mt * 64;
    const int lm = tid >> 2;
    const int lkb = tid & 3;

    const int mrow = m0 + lm;
    const int tl = mrow >> 6;
    const int b  = mrow & 63;
    const int tglob = (d == 0) ? (chunk * CHUNK + tl) : (TLEN - 1 - (chunk * CHUNK + tl));
    const float* Arow0 = features + ((size_t)b * TLEN + tglob) * FEAT;
    const unsigned short* Arow1 = x1 + ((size_t)tglob * BATCH + b) * FEAT;

    f32x4 acc[4];
    #pragma unroll
    for (int i = 0; i < 4; ++i) acc[i] = 0.0f;

    const int fr = lane & 15, quad = lane >> 4;

    for (int k0 = 0; k0 < FEAT; k0 += 32) {
        if (layer == 0) {
            float4 a0 = *(const float4*)(Arow0 + k0 + lkb * 8);
            float4 a1 = *(const float4*)(Arow0 + k0 + lkb * 8 + 4);
            unsigned short* dst = &Alds[lm][lkb * 8];
            dst[0] = f2bf(a0.x); dst[1] = f2bf(a0.y);
            dst[2] = f2bf(a0.z); dst[3] = f2bf(a0.w);
            dst[4] = f2bf(a1.x); dst[5] = f2bf(a1.y);
            dst[6] = f2bf(a1.z); dst[7] = f2bf(a1.w);
        } else {
            uint4 a = *(const uint4*)(Arow1 + k0 + lkb * 8);
            *(uint4*)&Alds[lm][lkb * 8] = a;
        }
        uint4 bv = *(const uint4*)(Wt + (size_t)lm * FEAT + k0 + lkb * 8);
        *(uint4*)&Blds[lm][lkb * 8] = bv;
        __syncthreads();

        bf16x8 af = *(const bf16x8*)&Alds[wave * 16 + fr][quad * 8];
        #pragma unroll
        for (int nt = 0; nt < 4; ++nt) {
            bf16x8 bf = *(const bf16x8*)&Blds[nt * 16 + fr][quad * 8];
            acc[nt] = __builtin_amdgcn_mfma_f32_16x16x32_bf16(af, bf, acc[nt], 0, 0, 0);
        }
        __syncthreads();
    }

    const int ldoff = layer * 2 + d;
    #pragma unroll
    for (int nt = 0; nt < 4; ++nt) {
        const int n = n0 + nt * 16 + fr;
        #pragma unroll
        for (int r = 0; r < 4; ++r) {
            const int m2 = m0 + wave * 16 + quad * 4 + r;
            const int tl2 = m2 >> 6, b2 = m2 & 63;
            float v = acc[nt][r];
            if (n < FIVEH) {
                v += bx[(size_t)ldoff * FIVEH + n] + bh[(size_t)ldoff * FIVEH + n];
                const int g = n >> 8, j = n & 255;
                gx_c[((((size_t)d * CHUNK + tl2) * 5 + g) * HDIM + j) * BATCH + b2] = f2bf(v);
            } else {
                const int j = n - FIVEH;
                v += bp[(size_t)ldoff * HDIM + j];
                px_c[(((size_t)d * CHUNK + tl2) * HDIM + j) * BATCH + b2] = f2bf(v);
            }
        }
    }
}

// ---------------------------------------------------------------------------
// Recurrence with SELF-VALIDATING tagged h-exchange. No flags, no fences,
// no per-step barriers, no LDS, no inline asm.
//
// hbuf: [parity][d][b][jdim] u32 = (tag<<16)|bf16(h), tag = global step gs
// (monotonic across all 32 dispatches, max 2047; 0xAAAA poison never matches
// -> no init kernel). All hbuf ops are relaxed agent-scope atomics
// (sc0 sc1: bypass L1+L2, coherent at L3 across XCDs). Aligned dword
// atomics cannot tear, so tag+data are inseparable.
//
// Overwrite-safety of the 2-deep parity buffer with free-running waves:
// only same-mw waves (across the 8 WGs of a direction) exchange data.
// A wave publishes h(t+1) strictly after its loads of h(t) completed
// (register data dependency: stores depend on MFMA results which depend on
// loaded h). A producer overwrites the slot of h(t) only when publishing
// h(t+2), which requires tag-(t+1) words from every same-mw wave -- each of
// which had therefore finished reading h(t). Tags are monotonic -> no ABA.
//
// All retry loops are bounded (RETRY_GUARD): a broken protocol produces a
// reported wrong answer, never a hang.
// ---------------------------------------------------------------------------
__global__ __launch_bounds__(256, 1) void recur_kernel(
    const unsigned short* __restrict__ gx_c,   // [d][CHUNK][5][256][64] bf16
    const unsigned short* __restrict__ px_c,   // [d][CHUNK][256][64]    bf16
    const unsigned short* __restrict__ Wh_t,   // [l][d][1280][256]      bf16
    unsigned short* __restrict__ x1,           // [T][B][512] bf16
    float* __restrict__ out,                   // [B][T][512] fp32
    float* __restrict__ cbuf,                  // [2][64][256] fp32
    unsigned int* __restrict__ hbuf,           // [2 parity][2 d][64][256] tagged u32
    int layer, int chunk)
{
    const int blk = blockIdx.x;
    const int d = blk >> 3, wg = blk & 7;
    const int tid = threadIdx.x;
    const int wave = tid >> 6, lane = tid & 63;
    const int mw = wave >> 1, jh = wave & 1;
    const int col = lane & 15, quad = lane >> 4;
    const int jg = wg * 32 + jh * 16 + col;   // this lane's j column

    // ---- persistent B fragments: Wh columns for gates 0..4 at column jg ----
    bf16x8 bfr[5][8];
    const unsigned short* Wb = Wh_t + (size_t)(layer * 2 + d) * FIVEH * HDIM;
    #pragma unroll
    for (int g = 0; g < 5; ++g)
        #pragma unroll
        for (int ks = 0; ks < 8; ++ks)
            bfr[g][ks] = *(const bf16x8*)(Wb + (size_t)(g * HDIM + jg) * HDIM + ks * 32 + quad * 8);

    // ---- c state (lane-resident) ----
    float cst[2][4];
    #pragma unroll
    for (int mt = 0; mt < 2; ++mt)
        #pragma unroll
        for (int r = 0; r < 4; ++r) {
            const int b = (2 * mw + mt) * 16 + quad * 4 + r;
            cst[mt][r] = (chunk == 0) ? 0.0f
                       : cbuf[((size_t)d * BATCH + b) * HDIM + jg];
        }

    const int base = layer * TLEN + chunk * CHUNK;

    for (int s = 0; s < CHUNK; ++s) {
        const int gs = base + s;

        // ---- gx / px prefetch (cached; latency hides under the tagged poll) ----
        ushort4 gxv[2][5], pxv[2];
        #pragma unroll
        for (int mt = 0; mt < 2; ++mt) {
            const size_t bb = (2 * mw + mt) * 16 + quad * 4;
            #pragma unroll
            for (int g = 0; g < 5; ++g)
                gxv[mt][g] = *(const ushort4*)(gx_c + ((((size_t)d * CHUNK + s) * 5 + g) * HDIM + jg) * BATCH + bb);
            pxv[mt] = *(const ushort4*)(px_c + (((size_t)d * CHUNK + s) * HDIM + jg) * BATCH + bb);
        }

        // ---- GEMM: z-slice = h @ Wh_slice, via tagged self-validating loads ----
        f32x4 acc[2][5];
        #pragma unroll
        for (int mt = 0; mt < 2; ++mt)
            #pragma unroll
            for (int g = 0; g < 5; ++g) acc[mt][g] = 0.0f;

        if ((gs & (TLEN - 1)) != 0) {   // h==0 at the start of each layer
            const unsigned want = (unsigned)(gs - 1);
            const u64* h64 = (const u64*)(hbuf + (size_t)(((gs + 1) & 1) * 2 + d) * BATCH * HDIM);

            // issue all 64 dwordx2 atomic loads (both m-tiles) up front;
            // the compiler inserts one bulk vmcnt wait before first use.
            u64 w[2][8][4];
            #pragma unroll
            for (int mt = 0; mt < 2; ++mt) {
                const size_t rb = (size_t)((2 * mw + mt) * 16 + col) * (HDIM / 2) + quad * 4;
                #pragma unroll
                for (int ks = 0; ks < 8; ++ks)
                    #pragma unroll
                    for (int q = 0; q < 4; ++q)
                        w[mt][ks][q] = ALOAD(h64 + rb + ks * 16 + q);
            }

            #pragma unroll
            for (int ks = 0; ks < 8; ++ks) {
                #pragma unroll
                for (int mt = 0; mt < 2; ++mt) {
                    const u64* ub = h64 + (size_t)((2 * mw + mt) * 16 + col) * (HDIM / 2)
                                    + quad * 4 + ks * 16;
                    u64 a0 = w[mt][ks][0], a1 = w[mt][ks][1];
                    u64 a2 = w[mt][ks][2], a3 = w[mt][ks][3];
                    int guard = 0;
                    while (!( ((unsigned)(a0 >> 16) & 0xFFFFu) == want && (unsigned)(a0 >> 48) == want &&
                              ((unsigned)(a1 >> 16) & 0xFFFFu) == want && (unsigned)(a1 >> 48) == want &&
                              ((unsigned)(a2 >> 16) & 0xFFFFu) == want && (unsigned)(a2 >> 48) == want &&
                              ((unsigned)(a3 >> 16) & 0xFFFFu) == want && (unsigned)(a3 >> 48) == want )) {
                        if (++guard > RETRY_GUARD) break;   // reported failure, never a hang
                        a0 = ALOAD(ub + 0); a1 = ALOAD(ub + 1);
                        a2 = ALOAD(ub + 2); a3 = ALOAD(ub + 3);
                    }
                    // strip tags, pack to bf16x8 (k-elems: lo16 of each u32)
                    union { unsigned uw[4]; bf16x8 v; } u;
                    u.uw[0] = ((unsigned)a0 & 0xFFFFu) | (((unsigned)(a0 >> 32)) << 16);
                    u.uw[1] = ((unsigned)a1 & 0xFFFFu) | (((unsigned)(a1 >> 32)) << 16);
                    u.uw[2] = ((unsigned)a2 & 0xFFFFu) | (((unsigned)(a2 >> 32)) << 16);
                    u.uw[3] = ((unsigned)a3 & 0xFFFFu) | (((unsigned)(a3 >> 32)) << 16);
                    #pragma unroll
                    for (int g = 0; g < 5; ++g)
                        acc[mt][g] = __builtin_amdgcn_mfma_f32_16x16x32_bf16(
                            u.v, bfr[g][ks], acc[mt][g], 0, 0, 0);
                }
            }
        }

        const int tpos = chunk * CHUNK + s;
        const int tglob = d ? (TLEN - 1 - tpos) : tpos;
        const unsigned tagw = (unsigned)gs;
        unsigned int* hdst = hbuf + (size_t)((gs & 1) * 2 + d) * BATCH * HDIM;

        // ---- gate math; h published as tagged dword atomics (fire-and-forget,
        //      compiler tracks the store-data hazard) ----
        unsigned short hbv[2][4];
        float hfv[2][4];
        #pragma unroll
        for (int mt = 0; mt < 2; ++mt) {
            const unsigned short* gq0 = (const unsigned short*)&gxv[mt][0];
            const unsigned short* gq1 = (const unsigned short*)&gxv[mt][1];
            const unsigned short* gq2 = (const unsigned short*)&gxv[mt][2];
            const unsigned short* gq3 = (const unsigned short*)&gxv[mt][3];
            const unsigned short* gq4 = (const unsigned short*)&gxv[mt][4];
            const unsigned short* pq  = (const unsigned short*)&pxv[mt];
            #pragma unroll
            for (int r = 0; r < 4; ++r) {
                const float z0 = acc[mt][0][r] + bf2f(gq0[r]);
                const float z1 = acc[mt][1][r] + bf2f(gq1[r]);
                const float z2 = acc[mt][2][r] + bf2f(gq2[r]);
                const float z3 = acc[mt][3][r] + bf2f(gq3[r]);
                const float z4 = acc[mt][4][r] + bf2f(gq4[r]);
                const float p  = bf2f(pq[r]);
                const float ig = sigf(z0);
                const float og = sigf(z1);
                const float fg = sigf(z2);
                const float ug = tanhfast(z3);
                const float rg = sigf(z4);
                const float cc = ig * ug + fg * cst[mt][r];
                cst[mt][r] = cc;
                const float hh = og * tanhfast(cc);
                const float h = rg * hh + (1.0f - rg) * p;
                const int b = (2 * mw + mt) * 16 + quad * 4 + r;
                const unsigned short hb = f2bf(h);
                ASTORE(hdst + (size_t)b * HDIM + jg, (tagw << 16) | (unsigned)hb);
                hbv[mt][r] = hb;
                hfv[mt][r] = h;
            }
        }

        // ---- x1/out stores (cached; drain overlaps next step's poll) ----
        #pragma unroll
        for (int mt = 0; mt < 2; ++mt)
            #pragma unroll
            for (int r = 0; r < 4; ++r) {
                const int b = (2 * mw + mt) * 16 + quad * 4 + r;
                if (layer == 0)
                    x1[((size_t)tglob * BATCH + b) * 512 + d * HDIM + jg] = hbv[mt][r];
                else
                    out[((size_t)b * TLEN + tglob) * 512 + d * HDIM + jg] = hfv[mt][r];
            }
    }

    // ---- persist c for next chunk ----
    #pragma unroll
    for (int mt = 0; mt < 2; ++mt)
        #pragma unroll
        for (int r = 0; r < 4; ++r) {
            const int b = (2 * mw + mt) * 16 + quad * 4 + r;
            cbuf[((size_t)d * BATCH + b) * HDIM + jg] = cst[mt][r];
        }
}

// ---------------------------------------------------------------------------
extern "C" void kernel_launch(void* const* d_in, const int* in_sizes, int n_in,
                              void* d_out, int out_size, void* d_ws, size_t ws_size,
                              hipStream_t stream) {
    const float* features = (const float*)d_in[0];
    const float* Wx = (const float*)d_in[1];
    const float* bx = (const float*)d_in[2];
    const float* Wh = (const float*)d_in[3];
    const float* bh = (const float*)d_in[4];
    const float* Wp = (const float*)d_in[5];
    const float* bp = (const float*)d_in[6];
    float* out = (float*)d_out;

    char* ws = (char*)d_ws;
    size_t off = 0;
    auto alloc = [&](size_t bytes) -> void* {
        void* p = ws + off;
        off += (bytes + 255) & ~(size_t)255;
        return p;
    };
    unsigned short* Wx_t = (unsigned short*)alloc((size_t)LAYERS * DIRS * FIVEH * FEAT * 2);
    unsigned short* Wh_t = (unsigned short*)alloc((size_t)LAYERS * DIRS * FIVEH * HDIM * 2);
    unsigned short* Wp_t = (unsigned short*)alloc((size_t)LAYERS * DIRS * HDIM * FEAT * 2);
    unsigned short* x1   = (unsigned short*)alloc((size_t)TLEN * BATCH * 512 * 2);
    unsigned short* gx_c = (unsigned short*)alloc((size_t)DIRS * CHUNK * BATCH * FIVEH * 2);
    unsigned short* px_c = (unsigned short*)alloc((size_t)DIRS * CHUNK * BATCH * HDIM * 2);
    float* cbuf = (float*)alloc((size_t)DIRS * BATCH * HDIM * 4);
    unsigned int* hbuf = (unsigned int*)alloc((size_t)2 * DIRS * BATCH * HDIM * 4);

    castT_kernel<<<dim3(FIVEH / 32, FEAT / 32, 4), 256, 0, stream>>>(Wx, Wx_t, FEAT, FIVEH);
    castT_kernel<<<dim3(FIVEH / 32, HDIM / 32, 4), 256, 0, stream>>>(Wh, Wh_t, HDIM, FIVEH);
    castT_kernel<<<dim3(HDIM / 32, FEAT / 32, 4), 256, 0, stream>>>(Wp, Wp_t, FEAT, HDIM);

    for (int l = 0; l < LAYERS; ++l) {
        for (int c = 0; c < NCHUNK; ++c) {
            proj_kernel<<<dim3(24, 64, 2), 256, 0, stream>>>(
                features, x1, Wx_t, Wp_t, bx, bh, bp, gx_c, px_c, l, c);
            recur_kernel<<<DIRS * NW, 256, 0, stream>>>(
                gx_c, px_c, Wh_t, x1, out, cbuf, hbuf, l, c);
        }
    }
}

// Round 6
// 29886.392 us; speedup vs baseline: 1.2766x; 1.2766x over previous
//
#include <hip/hip_runtime.h>
#include <hip/hip_bf16.h>

// Problem constants
#define LAYERS 2
#define DIRS   2
#define FEAT   512
#define HDIM   256
#define BATCH  64
#define TLEN   1024
#define FIVEH  1280
#define CHUNK  64          // timesteps per chunk
#define NCHUNK (TLEN / CHUNK)
#define NW     8           // workgroups per direction in recurrence
#define RETRY_GUARD 8192   // bounded retry ROUNDS per step: broken protocol -> reported failure, not hang

typedef short bf16x8 __attribute__((ext_vector_type(8)));
typedef float f32x4  __attribute__((ext_vector_type(4)));
typedef unsigned long long u64;

// Relaxed agent-scope atomics: compile to global_{load,store} ... sc0 sc1 —
// bypass L1/L2, coherent at the Infinity Cache across XCDs. Compiler-managed,
// so all store-data / load-use register hazards are tracked by LLVM's
// waitcnt pass (no inline-asm memory ops — the r3/r4 bug class).
#define ALOAD(p)    __hip_atomic_load((p),      __ATOMIC_RELAXED, __HIP_MEMORY_SCOPE_AGENT)
#define ASTORE(p,v) __hip_atomic_store((p),(v), __ATOMIC_RELAXED, __HIP_MEMORY_SCOPE_AGENT)

__device__ __forceinline__ unsigned short f2bf(float x) {
    unsigned u = __float_as_uint(x);
    unsigned r = (u + 0x7fffu + ((u >> 16) & 1u)) >> 16;
    return (unsigned short)r;
}
__device__ __forceinline__ float bf2f(unsigned short h) {
    return __uint_as_float(((unsigned)h) << 16);
}
__device__ __forceinline__ float sigf(float x) {
    return 1.0f / (1.0f + __expf(-x));
}
__device__ __forceinline__ float tanhfast(float x) {
    return 1.0f - 2.0f / (__expf(2.0f * x) + 1.0f);
}

// ---------------------------------------------------------------------------
// Transpose + cast: src fp32 [K][N] (per (l,d) slab) -> dst bf16 [N][K]
// ---------------------------------------------------------------------------
__global__ __launch_bounds__(256) void castT_kernel(
    const float* __restrict__ src, unsigned short* __restrict__ dst, int K, int N)
{
    __shared__ float tile[32][33];
    const int n0 = blockIdx.x * 32, k0 = blockIdx.y * 32;
    const size_t slab = (size_t)blockIdx.z * K * N;
    src += slab; dst += slab;
    const int tx = threadIdx.x & 31, ty = threadIdx.x >> 5;
    #pragma unroll
    for (int r = 0; r < 32; r += 8)
        tile[ty + r][tx] = src[(size_t)(k0 + ty + r) * N + (n0 + tx)];
    __syncthreads();
    #pragma unroll
    for (int r = 0; r < 32; r += 8)
        dst[(size_t)(n0 + ty + r) * K + (k0 + tx)] = f2bf(tile[tx][ty + r]);
}

// ---------------------------------------------------------------------------
// Projection GEMM for one chunk (unchanged, proven across r0-r5)
// ---------------------------------------------------------------------------
__global__ __launch_bounds__(256) void proj_kernel(
    const float* __restrict__ features,
    const unsigned short* __restrict__ x1,
    const unsigned short* __restrict__ Wx_t,   // [l][d][1280][512] bf16
    const unsigned short* __restrict__ Wp_t,   // [l][d][256][512]  bf16
    const float* __restrict__ bx, const float* __restrict__ bh,
    const float* __restrict__ bp,
    unsigned short* __restrict__ gx_c,
    unsigned short* __restrict__ px_c,
    int layer, int chunk)
{
    const int ntb = blockIdx.x;
    const int mt  = blockIdx.y;
    const int d   = blockIdx.z;
    const int tid = threadIdx.x;
    const int wave = tid >> 6, lane = tid & 63;

    __shared__ __align__(16) unsigned short Alds[64][40];
    __shared__ __align__(16) unsigned short Blds[64][40];

    const int n0 = ntb * 64;
    const bool isWx = (n0 < FIVEH);
    const unsigned short* Wt = isWx
        ? (Wx_t + ((size_t)(layer * 2 + d) * FIVEH + n0) * FEAT)
        : (Wp_t + ((size_t)(layer * 2 + d) * HDIM + (n0 - FIVEH)) * FEAT);

    const int m0 = mt * 64;
    const int lm = tid >> 2;
    const int lkb = tid & 3;

    const int mrow = m0 + lm;
    const int tl = mrow >> 6;
    const int b  = mrow & 63;
    const int tglob = (d == 0) ? (chunk * CHUNK + tl) : (TLEN - 1 - (chunk * CHUNK + tl));
    const float* Arow0 = features + ((size_t)b * TLEN + tglob) * FEAT;
    const unsigned short* Arow1 = x1 + ((size_t)tglob * BATCH + b) * FEAT;

    f32x4 acc[4];
    #pragma unroll
    for (int i = 0; i < 4; ++i) acc[i] = 0.0f;

    const int fr = lane & 15, quad = lane >> 4;

    for (int k0 = 0; k0 < FEAT; k0 += 32) {
        if (layer == 0) {
            float4 a0 = *(const float4*)(Arow0 + k0 + lkb * 8);
            float4 a1 = *(const float4*)(Arow0 + k0 + lkb * 8 + 4);
            unsigned short* dst = &Alds[lm][lkb * 8];
            dst[0] = f2bf(a0.x); dst[1] = f2bf(a0.y);
            dst[2] = f2bf(a0.z); dst[3] = f2bf(a0.w);
            dst[4] = f2bf(a1.x); dst[5] = f2bf(a1.y);
            dst[6] = f2bf(a1.z); dst[7] = f2bf(a1.w);
        } else {
            uint4 a = *(const uint4*)(Arow1 + k0 + lkb * 8);
            *(uint4*)&Alds[lm][lkb * 8] = a;
        }
        uint4 bv = *(const uint4*)(Wt + (size_t)lm * FEAT + k0 + lkb * 8);
        *(uint4*)&Blds[lm][lkb * 8] = bv;
        __syncthreads();

        bf16x8 af = *(const bf16x8*)&Alds[wave * 16 + fr][quad * 8];
        #pragma unroll
        for (int nt = 0; nt < 4; ++nt) {
            bf16x8 bf = *(const bf16x8*)&Blds[nt * 16 + fr][quad * 8];
            acc[nt] = __builtin_amdgcn_mfma_f32_16x16x32_bf16(af, bf, acc[nt], 0, 0, 0);
        }
        __syncthreads();
    }

    const int ldoff = layer * 2 + d;
    #pragma unroll
    for (int nt = 0; nt < 4; ++nt) {
        const int n = n0 + nt * 16 + fr;
        #pragma unroll
        for (int r = 0; r < 4; ++r) {
            const int m2 = m0 + wave * 16 + quad * 4 + r;
            const int tl2 = m2 >> 6, b2 = m2 & 63;
            float v = acc[nt][r];
            if (n < FIVEH) {
                v += bx[(size_t)ldoff * FIVEH + n] + bh[(size_t)ldoff * FIVEH + n];
                const int g = n >> 8, j = n & 255;
                gx_c[((((size_t)d * CHUNK + tl2) * 5 + g) * HDIM + j) * BATCH + b2] = f2bf(v);
            } else {
                const int j = n - FIVEH;
                v += bp[(size_t)ldoff * HDIM + j];
                px_c[(((size_t)d * CHUNK + tl2) * HDIM + j) * BATCH + b2] = f2bf(v);
            }
        }
    }
}

// ---------------------------------------------------------------------------
// Recurrence with SELF-VALIDATING tagged h-exchange. No flags, no fences,
// no per-step barriers, no LDS, no inline asm.
//
// hbuf: [parity][d][b][jdim] u32 = (tag<<16)|bf16(h), tag = global step gs.
// All hbuf ops are relaxed agent-scope atomics (sc0 sc1: bypass L1+L2,
// coherent at L3 across XCDs). Aligned u32/u64 atomics cannot tear.
// 0xAAAA poison never matches a tag -> no init kernel needed.
//
// r5 LESSON (measured 18.4 us/step): retrying stale units ONE AT A TIME
// serializes up to 16 L3 round-trips per step. This version does BULK
// RETRY ROUNDS: check all 64 words; if any stale, re-issue ALL 64 loads
// and re-check. Reload-all costs the same latency as reload-one (the step
// is latency-bound, not bandwidth-bound), so each round is ~1 RTT and the
// expected round count is 1-2.
//
// Overwrite-safety of the 2-deep parity buffer (unchanged from r5, which
// passed): a producer overwrites the slot of h(t) only when publishing
// h(t+2), which requires tag-(t+1) words from every same-mw wave, each of
// which had finished reading h(t) first (register data dependencies).
// Tags monotonic -> no ABA. Retry rounds bounded -> reported failure,
// never a hang.
// ---------------------------------------------------------------------------
__global__ __launch_bounds__(256, 1) void recur_kernel(
    const unsigned short* __restrict__ gx_c,   // [d][CHUNK][5][256][64] bf16
    const unsigned short* __restrict__ px_c,   // [d][CHUNK][256][64]    bf16
    const unsigned short* __restrict__ Wh_t,   // [l][d][1280][256]      bf16
    unsigned short* __restrict__ x1,           // [T][B][512] bf16
    float* __restrict__ out,                   // [B][T][512] fp32
    float* __restrict__ cbuf,                  // [2][64][256] fp32
    unsigned int* __restrict__ hbuf,           // [2 parity][2 d][64][256] tagged u32
    int layer, int chunk)
{
    const int blk = blockIdx.x;
    const int d = blk >> 3, wg = blk & 7;
    const int tid = threadIdx.x;
    const int wave = tid >> 6, lane = tid & 63;
    const int mw = wave >> 1, jh = wave & 1;
    const int col = lane & 15, quad = lane >> 4;
    const int jg = wg * 32 + jh * 16 + col;   // this lane's j column

    // ---- persistent B fragments: Wh columns for gates 0..4 at column jg ----
    bf16x8 bfr[5][8];
    const unsigned short* Wb = Wh_t + (size_t)(layer * 2 + d) * FIVEH * HDIM;
    #pragma unroll
    for (int g = 0; g < 5; ++g)
        #pragma unroll
        for (int ks = 0; ks < 8; ++ks)
            bfr[g][ks] = *(const bf16x8*)(Wb + (size_t)(g * HDIM + jg) * HDIM + ks * 32 + quad * 8);

    // ---- c state (lane-resident) ----
    float cst[2][4];
    #pragma unroll
    for (int mt = 0; mt < 2; ++mt)
        #pragma unroll
        for (int r = 0; r < 4; ++r) {
            const int b = (2 * mw + mt) * 16 + quad * 4 + r;
            cst[mt][r] = (chunk == 0) ? 0.0f
                       : cbuf[((size_t)d * BATCH + b) * HDIM + jg];
        }

    const int base = layer * TLEN + chunk * CHUNK;

    for (int s = 0; s < CHUNK; ++s) {
        const int gs = base + s;

        // ---- gx / px prefetch (cached; latency hides under the tagged poll) ----
        ushort4 gxv[2][5], pxv[2];
        #pragma unroll
        for (int mt = 0; mt < 2; ++mt) {
            const size_t bb = (2 * mw + mt) * 16 + quad * 4;
            #pragma unroll
            for (int g = 0; g < 5; ++g)
                gxv[mt][g] = *(const ushort4*)(gx_c + ((((size_t)d * CHUNK + s) * 5 + g) * HDIM + jg) * BATCH + bb);
            pxv[mt] = *(const ushort4*)(px_c + (((size_t)d * CHUNK + s) * HDIM + jg) * BATCH + bb);
        }

        // ---- GEMM: z-slice = h @ Wh_slice, via tagged self-validating loads ----
        f32x4 acc[2][5];
        #pragma unroll
        for (int mt = 0; mt < 2; ++mt)
            #pragma unroll
            for (int g = 0; g < 5; ++g) acc[mt][g] = 0.0f;

        if ((gs & (TLEN - 1)) != 0) {   // h==0 at the start of each layer
            const unsigned want = (unsigned)(gs - 1);
            const u64* h64 = (const u64*)(hbuf + (size_t)(((gs + 1) & 1) * 2 + d) * BATCH * HDIM);

            // per-lane base offsets (u64 units) for the two m-tiles
            const size_t rb0 = (size_t)((2 * mw + 0) * 16 + col) * (HDIM / 2) + quad * 4;
            const size_t rb1 = (size_t)((2 * mw + 1) * 16 + col) * (HDIM / 2) + quad * 4;

            // initial bulk issue of all 64 u64 loads
            u64 w[2][8][4];
            #pragma unroll
            for (int ks = 0; ks < 8; ++ks)
                #pragma unroll
                for (int q = 0; q < 4; ++q) {
                    w[0][ks][q] = ALOAD(h64 + rb0 + ks * 16 + q);
                    w[1][ks][q] = ALOAD(h64 + rb1 + ks * 16 + q);
                }

            // BULK retry rounds: all-or-nothing re-issue (1 RTT per round)
            int rounds = 0;
            while (true) {
                bool ok = true;
                #pragma unroll
                for (int mt = 0; mt < 2; ++mt)
                    #pragma unroll
                    for (int ks = 0; ks < 8; ++ks)
                        #pragma unroll
                        for (int q = 0; q < 4; ++q) {
                            const u64 v = w[mt][ks][q];
                            ok = ok && (((unsigned)(v >> 16) & 0xFFFFu) == want)
                                    && ((unsigned)(v >> 48) == want);
                        }
                if (ok || ++rounds > RETRY_GUARD) break;   // bounded: never hangs
                #pragma unroll
                for (int ks = 0; ks < 8; ++ks)
                    #pragma unroll
                    for (int q = 0; q < 4; ++q) {
                        w[0][ks][q] = ALOAD(h64 + rb0 + ks * 16 + q);
                        w[1][ks][q] = ALOAD(h64 + rb1 + ks * 16 + q);
                    }
            }

            // unpack (strip tags, pack pairs to bf16) + MFMA
            #pragma unroll
            for (int ks = 0; ks < 8; ++ks)
                #pragma unroll
                for (int mt = 0; mt < 2; ++mt) {
                    const u64 a0 = w[mt][ks][0], a1 = w[mt][ks][1];
                    const u64 a2 = w[mt][ks][2], a3 = w[mt][ks][3];
                    union { unsigned uw[4]; bf16x8 v; } u;
                    u.uw[0] = ((unsigned)a0 & 0xFFFFu) | (((unsigned)(a0 >> 32)) << 16);
                    u.uw[1] = ((unsigned)a1 & 0xFFFFu) | (((unsigned)(a1 >> 32)) << 16);
                    u.uw[2] = ((unsigned)a2 & 0xFFFFu) | (((unsigned)(a2 >> 32)) << 16);
                    u.uw[3] = ((unsigned)a3 & 0xFFFFu) | (((unsigned)(a3 >> 32)) << 16);
                    #pragma unroll
                    for (int g = 0; g < 5; ++g)
                        acc[mt][g] = __builtin_amdgcn_mfma_f32_16x16x32_bf16(
                            u.v, bfr[g][ks], acc[mt][g], 0, 0, 0);
                }
        }

        const int tpos = chunk * CHUNK + s;
        const int tglob = d ? (TLEN - 1 - tpos) : tpos;
        const unsigned tagw = (unsigned)gs;
        unsigned int* hdst = hbuf + (size_t)((gs & 1) * 2 + d) * BATCH * HDIM;

        // ---- gate math; h published as tagged dword atomics (fire-and-forget,
        //      compiler tracks the store-data hazard) ----
        unsigned short hbv[2][4];
        float hfv[2][4];
        #pragma unroll
        for (int mt = 0; mt < 2; ++mt) {
            const unsigned short* gq0 = (const unsigned short*)&gxv[mt][0];
            const unsigned short* gq1 = (const unsigned short*)&gxv[mt][1];
            const unsigned short* gq2 = (const unsigned short*)&gxv[mt][2];
            const unsigned short* gq3 = (const unsigned short*)&gxv[mt][3];
            const unsigned short* gq4 = (const unsigned short*)&gxv[mt][4];
            const unsigned short* pq  = (const unsigned short*)&pxv[mt];
            #pragma unroll
            for (int r = 0; r < 4; ++r) {
                const float z0 = acc[mt][0][r] + bf2f(gq0[r]);
                const float z1 = acc[mt][1][r] + bf2f(gq1[r]);
                const float z2 = acc[mt][2][r] + bf2f(gq2[r]);
                const float z3 = acc[mt][3][r] + bf2f(gq3[r]);
                const float z4 = acc[mt][4][r] + bf2f(gq4[r]);
                const float p  = bf2f(pq[r]);
                const float ig = sigf(z0);
                const float og = sigf(z1);
                const float fg = sigf(z2);
                const float ug = tanhfast(z3);
                const float rg = sigf(z4);
                const float cc = ig * ug + fg * cst[mt][r];
                cst[mt][r] = cc;
                const float hh = og * tanhfast(cc);
                const float h = rg * hh + (1.0f - rg) * p;
                const int b = (2 * mw + mt) * 16 + quad * 4 + r;
                const unsigned short hb = f2bf(h);
                ASTORE(hdst + (size_t)b * HDIM + jg, (tagw << 16) | (unsigned)hb);
                hbv[mt][r] = hb;
                hfv[mt][r] = h;
            }
        }

        // ---- x1/out stores (cached; drain overlaps next step's poll) ----
        #pragma unroll
        for (int mt = 0; mt < 2; ++mt)
            #pragma unroll
            for (int r = 0; r < 4; ++r) {
                const int b = (2 * mw + mt) * 16 + quad * 4 + r;
                if (layer == 0)
                    x1[((size_t)tglob * BATCH + b) * 512 + d * HDIM + jg] = hbv[mt][r];
                else
                    out[((size_t)b * TLEN + tglob) * 512 + d * HDIM + jg] = hfv[mt][r];
            }
    }

    // ---- persist c for next chunk ----
    #pragma unroll
    for (int mt = 0; mt < 2; ++mt)
        #pragma unroll
        for (int r = 0; r < 4; ++r) {
            const int b = (2 * mw + mt) * 16 + quad * 4 + r;
            cbuf[((size_t)d * BATCH + b) * HDIM + jg] = cst[mt][r];
        }
}

// ---------------------------------------------------------------------------
extern "C" void kernel_launch(void* const* d_in, const int* in_sizes, int n_in,
                              void* d_out, int out_size, void* d_ws, size_t ws_size,
                              hipStream_t stream) {
    const float* features = (const float*)d_in[0];
    const float* Wx = (const float*)d_in[1];
    const float* bx = (const float*)d_in[2];
    const float* Wh = (const float*)d_in[3];
    const float* bh = (const float*)d_in[4];
    const float* Wp = (const float*)d_in[5];
    const float* bp = (const float*)d_in[6];
    float* out = (float*)d_out;

    char* ws = (char*)d_ws;
    size_t off = 0;
    auto alloc = [&](size_t bytes) -> void* {
        void* p = ws + off;
        off += (bytes + 255) & ~(size_t)255;
        return p;
    };
    unsigned short* Wx_t = (unsigned short*)alloc((size_t)LAYERS * DIRS * FIVEH * FEAT * 2);
    unsigned short* Wh_t = (unsigned short*)alloc((size_t)LAYERS * DIRS * FIVEH * HDIM * 2);
    unsigned short* Wp_t = (unsigned short*)alloc((size_t)LAYERS * DIRS * HDIM * FEAT * 2);
    unsigned short* x1   = (unsigned short*)alloc((size_t)TLEN * BATCH * 512 * 2);
    unsigned short* gx_c = (unsigned short*)alloc((size_t)DIRS * CHUNK * BATCH * FIVEH * 2);
    unsigned short* px_c = (unsigned short*)alloc((size_t)DIRS * CHUNK * BATCH * HDIM * 2);
    float* cbuf = (float*)alloc((size_t)DIRS * BATCH * HDIM * 4);
    unsigned int* hbuf = (unsigned int*)alloc((size_t)2 * DIRS * BATCH * HDIM * 4);

    castT_kernel<<<dim3(FIVEH / 32, FEAT / 32, 4), 256, 0, stream>>>(Wx, Wx_t, FEAT, FIVEH);
    castT_kernel<<<dim3(FIVEH / 32, HDIM / 32, 4), 256, 0, stream>>>(Wh, Wh_t, HDIM, FIVEH);
    castT_kernel<<<dim3(HDIM / 32, FEAT / 32, 4), 256, 0, stream>>>(Wp, Wp_t, FEAT, HDIM);

    for (int l = 0; l < LAYERS; ++l) {
        for (int c = 0; c < NCHUNK; ++c) {
            proj_kernel<<<dim3(24, 64, 2), 256, 0, stream>>>(
                features, x1, Wx_t, Wp_t, bx, bh, bp, gx_c, px_c, l, c);
            recur_kernel<<<DIRS * NW, 256, 0, stream>>>(
                gx_c, px_c, Wh_t, x1, out, cbuf, hbuf, l, c);
        }
    }
}

// Round 7
// 28030.499 us; speedup vs baseline: 1.3611x; 1.0662x over previous
//
#include <hip/hip_runtime.h>
#include <hip/hip_bf16.h>

// Problem constants
#define LAYERS 2
#define DIRS   2
#define FEAT   512
#define HDIM   256
#define BATCH  64
#define TLEN   1024
#define FIVEH  1280
#define CHUNK  64          // timesteps per chunk
#define NCHUNK (TLEN / CHUNK)
#define NW     8           // workgroups per direction in recurrence
#define SPIN_LIMIT (1 << 16)   // bounded poll: broken protocol -> reported failure, never a hang

typedef short bf16x8 __attribute__((ext_vector_type(8)));
typedef float f32x4  __attribute__((ext_vector_type(4)));
typedef unsigned long long u64;

// Relaxed agent-scope atomics: global_{load,store} ... sc0 sc1 — bypass
// L1/L2, coherent at the Infinity Cache across XCDs. Compiler-managed
// (register hazards tracked by LLVM's waitcnt pass; no asm memory ops).
#define ALOAD(p)    __hip_atomic_load((p),      __ATOMIC_RELAXED, __HIP_MEMORY_SCOPE_AGENT)
#define ASTORE(p,v) __hip_atomic_store((p),(v), __ATOMIC_RELAXED, __HIP_MEMORY_SCOPE_AGENT)

__device__ __forceinline__ unsigned short f2bf(float x) {
    unsigned u = __float_as_uint(x);
    unsigned r = (u + 0x7fffu + ((u >> 16) & 1u)) >> 16;
    return (unsigned short)r;
}
__device__ __forceinline__ float bf2f(unsigned short h) {
    return __uint_as_float(((unsigned)h) << 16);
}
__device__ __forceinline__ float sigf(float x) {
    return 1.0f / (1.0f + __expf(-x));
}
__device__ __forceinline__ float tanhfast(float x) {
    return 1.0f - 2.0f / (__expf(2.0f * x) + 1.0f);
}

// ---------------------------------------------------------------------------
// Transpose + cast: src fp32 [K][N] (per (l,d) slab) -> dst bf16 [N][K]
// ---------------------------------------------------------------------------
__global__ __launch_bounds__(256) void castT_kernel(
    const float* __restrict__ src, unsigned short* __restrict__ dst, int K, int N)
{
    __shared__ float tile[32][33];
    const int n0 = blockIdx.x * 32, k0 = blockIdx.y * 32;
    const size_t slab = (size_t)blockIdx.z * K * N;
    src += slab; dst += slab;
    const int tx = threadIdx.x & 31, ty = threadIdx.x >> 5;
    #pragma unroll
    for (int r = 0; r < 32; r += 8)
        tile[ty + r][tx] = src[(size_t)(k0 + ty + r) * N + (n0 + tx)];
    __syncthreads();
    #pragma unroll
    for (int r = 0; r < 32; r += 8)
        dst[(size_t)(n0 + ty + r) * K + (k0 + tx)] = f2bf(tile[tx][ty + r]);
}

// ---------------------------------------------------------------------------
// Zero the 64 per-wave step flags (ws poisoned 0xAA each call -> negative ints)
// ---------------------------------------------------------------------------
__global__ __launch_bounds__(64) void init_kernel(int* __restrict__ flags) {
    flags[threadIdx.x * 16] = 0;   // 64B stride per flag
}

// ---------------------------------------------------------------------------
// Projection GEMM for one chunk (unchanged, proven across r0-r6)
// ---------------------------------------------------------------------------
__global__ __launch_bounds__(256) void proj_kernel(
    const float* __restrict__ features,
    const unsigned short* __restrict__ x1,
    const unsigned short* __restrict__ Wx_t,   // [l][d][1280][512] bf16
    const unsigned short* __restrict__ Wp_t,   // [l][d][256][512]  bf16
    const float* __restrict__ bx, const float* __restrict__ bh,
    const float* __restrict__ bp,
    unsigned short* __restrict__ gx_c,
    unsigned short* __restrict__ px_c,
    int layer, int chunk)
{
    const int ntb = blockIdx.x;
    const int mt  = blockIdx.y;
    const int d   = blockIdx.z;
    const int tid = threadIdx.x;
    const int wave = tid >> 6, lane = tid & 63;

    __shared__ __align__(16) unsigned short Alds[64][40];
    __shared__ __align__(16) unsigned short Blds[64][40];

    const int n0 = ntb * 64;
    const bool isWx = (n0 < FIVEH);
    const unsigned short* Wt = isWx
        ? (Wx_t + ((size_t)(layer * 2 + d) * FIVEH + n0) * FEAT)
        : (Wp_t + ((size_t)(layer * 2 + d) * HDIM + (n0 - FIVEH)) * FEAT);

    const int m0 = mt * 64;
    const int lm = tid >> 2;
    const int lkb = tid & 3;

    const int mrow = m0 + lm;
    const int tl = mrow >> 6;
    const int b  = mrow & 63;
    const int tglob = (d == 0) ? (chunk * CHUNK + tl) : (TLEN - 1 - (chunk * CHUNK + tl));
    const float* Arow0 = features + ((size_t)b * TLEN + tglob) * FEAT;
    const unsigned short* Arow1 = x1 + ((size_t)tglob * BATCH + b) * FEAT;

    f32x4 acc[4];
    #pragma unroll
    for (int i = 0; i < 4; ++i) acc[i] = 0.0f;

    const int fr = lane & 15, quad = lane >> 4;

    for (int k0 = 0; k0 < FEAT; k0 += 32) {
        if (layer == 0) {
            float4 a0 = *(const float4*)(Arow0 + k0 + lkb * 8);
            float4 a1 = *(const float4*)(Arow0 + k0 + lkb * 8 + 4);
            unsigned short* dst = &Alds[lm][lkb * 8];
            dst[0] = f2bf(a0.x); dst[1] = f2bf(a0.y);
            dst[2] = f2bf(a0.z); dst[3] = f2bf(a0.w);
            dst[4] = f2bf(a1.x); dst[5] = f2bf(a1.y);
            dst[6] = f2bf(a1.z); dst[7] = f2bf(a1.w);
        } else {
            uint4 a = *(const uint4*)(Arow1 + k0 + lkb * 8);
            *(uint4*)&Alds[lm][lkb * 8] = a;
        }
        uint4 bv = *(const uint4*)(Wt + (size_t)lm * FEAT + k0 + lkb * 8);
        *(uint4*)&Blds[lm][lkb * 8] = bv;
        __syncthreads();

        bf16x8 af = *(const bf16x8*)&Alds[wave * 16 + fr][quad * 8];
        #pragma unroll
        for (int nt = 0; nt < 4; ++nt) {
            bf16x8 bf = *(const bf16x8*)&Blds[nt * 16 + fr][quad * 8];
            acc[nt] = __builtin_amdgcn_mfma_f32_16x16x32_bf16(af, bf, acc[nt], 0, 0, 0);
        }
        __syncthreads();
    }

    const int ldoff = layer * 2 + d;
    #pragma unroll
    for (int nt = 0; nt < 4; ++nt) {
        const int n = n0 + nt * 16 + fr;
        #pragma unroll
        for (int r = 0; r < 4; ++r) {
            const int m2 = m0 + wave * 16 + quad * 4 + r;
            const int tl2 = m2 >> 6, b2 = m2 & 63;
            float v = acc[nt][r];
            if (n < FIVEH) {
                v += bx[(size_t)ldoff * FIVEH + n] + bh[(size_t)ldoff * FIVEH + n];
                const int g = n >> 8, j = n & 255;
                gx_c[((((size_t)d * CHUNK + tl2) * 5 + g) * HDIM + j) * BATCH + b2] = f2bf(v);
            } else {
                const int j = n - FIVEH;
                v += bp[(size_t)ldoff * HDIM + j];
                px_c[(((size_t)d * CHUNK + tl2) * HDIM + j) * BATCH + b2] = f2bf(v);
            }
        }
    }
}

// ---------------------------------------------------------------------------
// Recurrence: PER-WAVE flag handshake, zero intra-WG barriers, zero fences.
//
// r5/r6 lesson: poll-on-data floods the fabric (2MB/round) -> 18-19 us/step.
// r0/r1 lesson: flag-notify + load-once works (7.6-8.2 us/step); its cost is
// structural (2 barriers/step, WG-level flags, whole-WG release drain).
// This version keeps the flag protocol but at WAVE granularity:
//
//  - flags[d][mw][wg][jh] (64 ints, 64B stride). Wave publishes its own flag
//    (value gs+1) after asm s_waitcnt vmcnt(0) drains its own h-stores. No
//    __syncthreads anywhere in the step loop; the two mw-groups per direction
//    are fully independent pipelines of 16 waves each.
//  - consumer: all 64 lanes poll the 16 flags of their (d,mw) group (lane L
//    -> wg=(L&15)>>1, jh=L&1); exit on __all(f >= gs). One coalesced dword
//    load per iteration -> negligible fabric load.
//  - flag observed >= gs  =>  producer's h-stores were acked at L3 before its
//    flag store issued (vmcnt(0) drain)  =>  af loads issued after the poll
//    read fresh data. No tags, no acquire fence needed.
//  - h exchanged as u32 payload words via ASTORE/ALOAD-u64 (instruction forms
//    proven correct in r5/r6); x1/out stores deferred past the flag publish.
//
// Parity overwrite-safety: producer stores h(s+2) into the slot of h(s) only
// after its poll saw all peer flags >= s+2, i.e. every peer finished step s+1,
// whose af-loads of h(s) were drained before that peer's s+1 flag. Monotonic
// flags -> no ABA. Poll bounded by SPIN_LIMIT -> never hangs.
// ---------------------------------------------------------------------------
__global__ __launch_bounds__(256, 1) void recur_kernel(
    const unsigned short* __restrict__ gx_c,   // [d][CHUNK][5][256][64] bf16
    const unsigned short* __restrict__ px_c,   // [d][CHUNK][256][64]    bf16
    const unsigned short* __restrict__ Wh_t,   // [l][d][1280][256]      bf16
    unsigned short* __restrict__ x1,           // [T][B][512] bf16
    float* __restrict__ out,                   // [B][T][512] fp32
    float* __restrict__ cbuf,                  // [2][64][256] fp32
    unsigned int* __restrict__ hbuf,           // [2 parity][2 d][64][256] u32 payload
    int* __restrict__ flags,                   // 64 flags, 64B stride
    int layer, int chunk)
{
    const int blk = blockIdx.x;
    const int d = blk >> 3, wg = blk & 7;
    const int tid = threadIdx.x;
    const int wave = tid >> 6, lane = tid & 63;
    const int mw = wave >> 1, jh = wave & 1;
    const int col = lane & 15, quad = lane >> 4;
    const int jg = wg * 32 + jh * 16 + col;   // this lane's j column

    // ---- persistent B fragments: Wh columns for gates 0..4 at column jg ----
    bf16x8 bfr[5][8];
    const unsigned short* Wb = Wh_t + (size_t)(layer * 2 + d) * FIVEH * HDIM;
    #pragma unroll
    for (int g = 0; g < 5; ++g)
        #pragma unroll
        for (int ks = 0; ks < 8; ++ks)
            bfr[g][ks] = *(const bf16x8*)(Wb + (size_t)(g * HDIM + jg) * HDIM + ks * 32 + quad * 8);

    // ---- c state (lane-resident) ----
    float cst[2][4];
    #pragma unroll
    for (int mt = 0; mt < 2; ++mt)
        #pragma unroll
        for (int r = 0; r < 4; ++r) {
            const int b = (2 * mw + mt) * 16 + quad * 4 + r;
            cst[mt][r] = (chunk == 0) ? 0.0f
                       : cbuf[((size_t)d * BATCH + b) * HDIM + jg];
        }

    const int base = layer * TLEN + chunk * CHUNK;

    // my flag (one per wave); poll set = 16 flags of my (d,mw) group
    int* myflag = &flags[((((d * 2 + mw) * NW) + wg) * 2 + jh) * 16];
    const int* pollflag = &flags[((((d * 2 + mw) * NW) + ((lane & 15) >> 1)) * 2 + (lane & 1)) * 16];

    for (int s = 0; s < CHUNK; ++s) {
        const int gs = base + s;

        // ---- gx / px prefetch (cached; latency hides under the poll) ----
        ushort4 gxv[2][5], pxv[2];
        #pragma unroll
        for (int mt = 0; mt < 2; ++mt) {
            const size_t bb = (2 * mw + mt) * 16 + quad * 4;
            #pragma unroll
            for (int g = 0; g < 5; ++g)
                gxv[mt][g] = *(const ushort4*)(gx_c + ((((size_t)d * CHUNK + s) * 5 + g) * HDIM + jg) * BATCH + bb);
            pxv[mt] = *(const ushort4*)(px_c + (((size_t)d * CHUNK + s) * HDIM + jg) * BATCH + bb);
        }

        // ---- GEMM: z-slice = h @ Wh_slice ----
        f32x4 acc[2][5];
        #pragma unroll
        for (int mt = 0; mt < 2; ++mt)
            #pragma unroll
            for (int g = 0; g < 5; ++g) acc[mt][g] = 0.0f;

        if ((gs & (TLEN - 1)) != 0) {   // h==0 at the start of each layer
            // ---- bounded all-lane poll of the 16 producer-wave flags ----
            int guard = 0;
            while (!__all(ALOAD(pollflag) >= gs) && ++guard < SPIN_LIMIT) { }
            asm volatile("" ::: "memory");   // compiler barrier: no load hoisting above the poll

            const u64* h64 = (const u64*)(hbuf + (size_t)(((gs + 1) & 1) * 2 + d) * BATCH * HDIM);

            #pragma unroll
            for (int mt = 0; mt < 2; ++mt) {
                // u64-unit base: row*(256 u32/2) + quad*4
                const size_t rb = (size_t)((2 * mw + mt) * 16 + col) * 128 + quad * 4;
                u64 w[8][4];
                #pragma unroll
                for (int ks = 0; ks < 8; ++ks)
                    #pragma unroll
                    for (int q = 0; q < 4; ++q)
                        w[ks][q] = ALOAD(h64 + rb + ks * 16 + q);

                #pragma unroll
                for (int ks = 0; ks < 8; ++ks) {
                    const u64 a0 = w[ks][0], a1 = w[ks][1];
                    const u64 a2 = w[ks][2], a3 = w[ks][3];
                    union { unsigned uw[4]; bf16x8 v; } u;
                    u.uw[0] = ((unsigned)a0 & 0xFFFFu) | (((unsigned)(a0 >> 32)) << 16);
                    u.uw[1] = ((unsigned)a1 & 0xFFFFu) | (((unsigned)(a1 >> 32)) << 16);
                    u.uw[2] = ((unsigned)a2 & 0xFFFFu) | (((unsigned)(a2 >> 32)) << 16);
                    u.uw[3] = ((unsigned)a3 & 0xFFFFu) | (((unsigned)(a3 >> 32)) << 16);
                    #pragma unroll
                    for (int g = 0; g < 5; ++g)
                        acc[mt][g] = __builtin_amdgcn_mfma_f32_16x16x32_bf16(
                            u.v, bfr[g][ks], acc[mt][g], 0, 0, 0);
                }
            }
        }

        const int tpos = chunk * CHUNK + s;
        const int tglob = d ? (TLEN - 1 - tpos) : tpos;
        unsigned int* hdst = hbuf + (size_t)((gs & 1) * 2 + d) * BATCH * HDIM;

        // ---- gate math; h published as u32 payload atomics (fire-and-forget) ----
        unsigned short hbv[2][4];
        float hfv[2][4];
        #pragma unroll
        for (int mt = 0; mt < 2; ++mt) {
            const unsigned short* gq0 = (const unsigned short*)&gxv[mt][0];
            const unsigned short* gq1 = (const unsigned short*)&gxv[mt][1];
            const unsigned short* gq2 = (const unsigned short*)&gxv[mt][2];
            const unsigned short* gq3 = (const unsigned short*)&gxv[mt][3];
            const unsigned short* gq4 = (const unsigned short*)&gxv[mt][4];
            const unsigned short* pq  = (const unsigned short*)&pxv[mt];
            #pragma unroll
            for (int r = 0; r < 4; ++r) {
                const float z0 = acc[mt][0][r] + bf2f(gq0[r]);
                const float z1 = acc[mt][1][r] + bf2f(gq1[r]);
                const float z2 = acc[mt][2][r] + bf2f(gq2[r]);
                const float z3 = acc[mt][3][r] + bf2f(gq3[r]);
                const float z4 = acc[mt][4][r] + bf2f(gq4[r]);
                const float p  = bf2f(pq[r]);
                const float ig = sigf(z0);
                const float og = sigf(z1);
                const float fg = sigf(z2);
                const float ug = tanhfast(z3);
                const float rg = sigf(z4);
                const float cc = ig * ug + fg * cst[mt][r];
                cst[mt][r] = cc;
                const float hh = og * tanhfast(cc);
                const float h = rg * hh + (1.0f - rg) * p;
                const int b = (2 * mw + mt) * 16 + quad * 4 + r;
                const unsigned short hb = f2bf(h);
                ASTORE(hdst + (size_t)b * HDIM + jg, (unsigned)hb);
                hbv[mt][r] = hb;
                hfv[mt][r] = h;
            }
        }

        // ---- release: drain OWN h-stores, then publish my wave's flag ----
        asm volatile("s_waitcnt vmcnt(0)" ::: "memory");
        if (lane == 0)
            ASTORE(myflag, gs + 1);

        // ---- deferred x1/out stores (cached); drain overlaps next step ----
        #pragma unroll
        for (int mt = 0; mt < 2; ++mt)
            #pragma unroll
            for (int r = 0; r < 4; ++r) {
                const int b = (2 * mw + mt) * 16 + quad * 4 + r;
                if (layer == 0)
                    x1[((size_t)tglob * BATCH + b) * 512 + d * HDIM + jg] = hbv[mt][r];
                else
                    out[((size_t)b * TLEN + tglob) * 512 + d * HDIM + jg] = hfv[mt][r];
            }
    }

    // ---- persist c for next chunk ----
    #pragma unroll
    for (int mt = 0; mt < 2; ++mt)
        #pragma unroll
        for (int r = 0; r < 4; ++r) {
            const int b = (2 * mw + mt) * 16 + quad * 4 + r;
            cbuf[((size_t)d * BATCH + b) * HDIM + jg] = cst[mt][r];
        }
}

// ---------------------------------------------------------------------------
extern "C" void kernel_launch(void* const* d_in, const int* in_sizes, int n_in,
                              void* d_out, int out_size, void* d_ws, size_t ws_size,
                              hipStream_t stream) {
    const float* features = (const float*)d_in[0];
    const float* Wx = (const float*)d_in[1];
    const float* bx = (const float*)d_in[2];
    const float* Wh = (const float*)d_in[3];
    const float* bh = (const float*)d_in[4];
    const float* Wp = (const float*)d_in[5];
    const float* bp = (const float*)d_in[6];
    float* out = (float*)d_out;

    char* ws = (char*)d_ws;
    size_t off = 0;
    auto alloc = [&](size_t bytes) -> void* {
        void* p = ws + off;
        off += (bytes + 255) & ~(size_t)255;
        return p;
    };
    unsigned short* Wx_t = (unsigned short*)alloc((size_t)LAYERS * DIRS * FIVEH * FEAT * 2);
    unsigned short* Wh_t = (unsigned short*)alloc((size_t)LAYERS * DIRS * FIVEH * HDIM * 2);
    unsigned short* Wp_t = (unsigned short*)alloc((size_t)LAYERS * DIRS * HDIM * FEAT * 2);
    unsigned short* x1   = (unsigned short*)alloc((size_t)TLEN * BATCH * 512 * 2);
    unsigned short* gx_c = (unsigned short*)alloc((size_t)DIRS * CHUNK * BATCH * FIVEH * 2);
    unsigned short* px_c = (unsigned short*)alloc((size_t)DIRS * CHUNK * BATCH * HDIM * 2);
    float* cbuf = (float*)alloc((size_t)DIRS * BATCH * HDIM * 4);
    unsigned int* hbuf = (unsigned int*)alloc((size_t)2 * DIRS * BATCH * HDIM * 4);
    int* flags = (int*)alloc((size_t)64 * 16 * 4);

    init_kernel<<<1, 64, 0, stream>>>(flags);
    castT_kernel<<<dim3(FIVEH / 32, FEAT / 32, 4), 256, 0, stream>>>(Wx, Wx_t, FEAT, FIVEH);
    castT_kernel<<<dim3(FIVEH / 32, HDIM / 32, 4), 256, 0, stream>>>(Wh, Wh_t, HDIM, FIVEH);
    castT_kernel<<<dim3(HDIM / 32, FEAT / 32, 4), 256, 0, stream>>>(Wp, Wp_t, FEAT, HDIM);

    for (int l = 0; l < LAYERS; ++l) {
        for (int c = 0; c < NCHUNK; ++c) {
            proj_kernel<<<dim3(24, 64, 2), 256, 0, stream>>>(
                features, x1, Wx_t, Wp_t, bx, bh, bp, gx_c, px_c, l, c);
            recur_kernel<<<DIRS * NW, 256, 0, stream>>>(
                gx_c, px_c, Wh_t, x1, out, cbuf, hbuf, flags, l, c);
        }
    }
}